// Round 5
// baseline (309.234 us; speedup 1.0000x reference)
//
#include <hip/hip_runtime.h>

// geodesic loss: mean(acos(clip((sum(ypred*ytrue per 3x3) - 1)*0.5, -1+eps, 1-eps)))
// B = 4,194,304 samples x 9 f32 per input; 302 MB read total.
//
// R1/R2 lesson: both ran at 2.7 TB/s delivered (113 us) with NO pipe saturated
// -> latency/MLP-bound: loads were drained (vmcnt(0)) every iteration.
// R3/R4 (resubmit; prior runs died to infra): double-buffered LDS staging via
// global_load_lds + COUNTED vmcnt so the next tile's 18 wave-loads stay in
// flight across the whole compute phase. Raw s_barrier (not __syncthreads)
// to avoid the implicit vmcnt(0) drain.

constexpr int TPB           = 256;
constexpr int NBLK          = 1024;              // 4 blocks/CU (LDS-limited)
constexpr int SAMP_PER_TILE = 256;
constexpr int TILE_F4       = SAMP_PER_TILE * 9 / 4;   // 576 float4 per input
constexpr int TILES_PER_BLK = 16;                // 1024*16*256 = 4,194,304 exactly
constexpr float EPSF = 1e-6f;

__device__ __forceinline__ void gload16_lds(const float4* g, float4* lds_base_uniform) {
    __builtin_amdgcn_global_load_lds(
        (const __attribute__((address_space(1))) void*)g,
        (__attribute__((address_space(3))) void*)lds_base_uniform,
        16, 0, 0);
}

__device__ __forceinline__ double block_reduce(double v) {
    __shared__ double sm[TPB / 64];
    const int lane = threadIdx.x & 63;
    const int wid  = threadIdx.x >> 6;
    #pragma unroll
    for (int off = 32; off > 0; off >>= 1) v += __shfl_down(v, off, 64);
    if (lane == 0) sm[wid] = v;
    __syncthreads();
    if (wid == 0) {
        v = (lane < TPB / 64) ? sm[lane] : 0.0;
        #pragma unroll
        for (int off = (TPB / 64) / 2; off > 0; off >>= 1) v += __shfl_down(v, off, 64);
    }
    return v;
}

__global__ __launch_bounds__(TPB) void geo_partial(
    const float* __restrict__ a, const float* __restrict__ b,
    double* __restrict__ partial, long long nsamp)
{
    __shared__ float4 sA[2][TILE_F4];   // 9216 B per buffer per input
    __shared__ float4 sB[2][TILE_F4];   // total 36,864 B -> 4 blocks/CU

    const int tid  = threadIdx.x;
    const int lane = tid & 63;
    const int wid  = tid >> 6;
    const float4* a4 = reinterpret_cast<const float4*>(a);
    const float4* b4 = reinterpret_cast<const float4*>(b);
    const long long tile0 = (long long)blockIdx.x * TILES_PER_BLK;

    // 18 wave-load instructions per tile (9 chunks x 2 inputs), round-robin by
    // wave: waves 0,1 issue 5 each; waves 2,3 issue 4 each. LDS dest is the
    // wave-uniform chunk base; HW scatters lane i to base + i*16 (m104/m108).
    auto stage = [&](int t, int bufsel) {
        const long long base = (tile0 + t) * TILE_F4;
        for (int i = wid; i < 18; i += 4) {
            const int c = i >> 1;
            if (i & 1) gload16_lds(b4 + base + c * 64 + lane, &sB[bufsel][c * 64]);
            else       gload16_lds(a4 + base + c * 64 + lane, &sA[bufsel][c * 64]);
        }
    };

    stage(0, 0);
    double acc = 0.0;

    for (int t = 0; t < TILES_PER_BLK; ++t) {
        const int cur = t & 1;
        if (t + 1 < TILES_PER_BLK) {
            stage(t + 1, cur ^ 1);             // next tile stays in flight over compute
            // wait ONLY for tile t's loads (leave tile t+1's outstanding)
            if (wid < 2) asm volatile("s_waitcnt vmcnt(5)" ::: "memory");
            else         asm volatile("s_waitcnt vmcnt(4)" ::: "memory");
        } else {
            asm volatile("s_waitcnt vmcnt(0)" ::: "memory");
        }
        __builtin_amdgcn_s_barrier();           // raw barrier: no implicit vmcnt(0)
        __builtin_amdgcn_sched_barrier(0);      // keep ds_reads below the barrier

        // one sample per thread; float stride 9 is odd -> worst 2-way aliasing (free)
        const float* pa = reinterpret_cast<const float*>(&sA[cur][0]) + 9 * tid;
        const float* pb = reinterpret_cast<const float*>(&sB[cur][0]) + 9 * tid;
        float dot = 0.0f;
        #pragma unroll
        for (int j = 0; j < 9; ++j) dot = fmaf(pa[j], pb[j], dot);

        const long long s = (tile0 + t) * SAMP_PER_TILE + tid;
        if (s < nsamp) {
            float c = (dot - 1.0f) * 0.5f;
            c = fminf(fmaxf(c, -1.0f + EPSF), 1.0f - EPSF);
            acc += (double)acosf(c);
        }

        __builtin_amdgcn_sched_barrier(0);      // keep compute above barrier2
        __builtin_amdgcn_s_barrier();           // all waves done reading buf[cur]
                                                // before next iter re-stages into it
    }

    const double r = block_reduce(acc);
    if (threadIdx.x == 0) partial[blockIdx.x] = r;
}

__global__ __launch_bounds__(TPB) void geo_final(
    const double* __restrict__ partial, float* __restrict__ out,
    int n, double inv_n)
{
    double acc = 0.0;
    for (int i = threadIdx.x; i < n; i += TPB) acc += partial[i];
    const double r = block_reduce(acc);
    if (threadIdx.x == 0) out[0] = (float)(r * inv_n);
}

extern "C" void kernel_launch(void* const* d_in, const int* in_sizes, int n_in,
                              void* d_out, int out_size, void* d_ws, size_t ws_size,
                              hipStream_t stream) {
    const float* a = (const float*)d_in[0];   // ypred [B,3,3] f32
    const float* b = (const float*)d_in[1];   // ytrue [B,3,3] f32
    float* out = (float*)d_out;               // scalar f32
    const long long nsamp = in_sizes[0] / 9;

    double* partial = (double*)d_ws;          // NBLK doubles; all written every launch

    geo_partial<<<NBLK, TPB, 0, stream>>>(a, b, partial, nsamp);
    geo_final<<<1, TPB, 0, stream>>>(partial, out, NBLK, 1.0 / (double)nsamp);
}

// Round 6
// 276.345 us; speedup vs baseline: 1.1190x; 1.1190x over previous
//
#include <hip/hip_runtime.h>

// geodesic loss: mean(acos(clip((sum(ypred*ytrue per 3x3) - 1)*0.5, -1+eps, 1-eps)))
// B = 4,194,304 samples x 9 f32 per input; 302 MB read, ~0 written.
//
// R1/R2/R3 all pin at ~112 us = 2.7 TB/s delivered, regardless of structure
// (scattered f4 / coalesced regs / LDS dbuf + counted vmcnt). Tile-period math
// shows ~7 us request completion time => memory system queue-saturated, not
// under-fed. Guide's measured kernels (m13 copy: 3.15 TB/s read + 3.15 write;
// m146 rmsnorm: ~3.3 read) suggest a ~3.2 TB/s read-direction ceiling.
// R5 single change: NT (non-temporal, aux=0x2) cache policy on the staging
// loads — zero-reuse workload; avoids L3 dirty-eviction churn from the
// harness's 302 MB input restore before every replay (WRITE_SIZE=33MB of
// writeback interference observed).

constexpr int TPB           = 256;
constexpr int NBLK          = 1024;              // 4 blocks/CU (LDS-limited)
constexpr int SAMP_PER_TILE = 256;
constexpr int TILE_F4       = SAMP_PER_TILE * 9 / 4;   // 576 float4 per input
constexpr int TILES_PER_BLK = 16;                // 1024*16*256 = 4,194,304 exactly
constexpr float EPSF = 1e-6f;

__device__ __forceinline__ void gload16_lds_nt(const float4* g, float4* lds_base_uniform) {
    __builtin_amdgcn_global_load_lds(
        (const __attribute__((address_space(1))) void*)g,
        (__attribute__((address_space(3))) void*)lds_base_uniform,
        16, 0, /*aux=NT*/ 2);
}

__device__ __forceinline__ double block_reduce(double v) {
    __shared__ double sm[TPB / 64];
    const int lane = threadIdx.x & 63;
    const int wid  = threadIdx.x >> 6;
    #pragma unroll
    for (int off = 32; off > 0; off >>= 1) v += __shfl_down(v, off, 64);
    if (lane == 0) sm[wid] = v;
    __syncthreads();
    if (wid == 0) {
        v = (lane < TPB / 64) ? sm[lane] : 0.0;
        #pragma unroll
        for (int off = (TPB / 64) / 2; off > 0; off >>= 1) v += __shfl_down(v, off, 64);
    }
    return v;
}

__global__ __launch_bounds__(TPB) void geo_partial(
    const float* __restrict__ a, const float* __restrict__ b,
    double* __restrict__ partial, long long nsamp)
{
    __shared__ float4 sA[2][TILE_F4];   // 9216 B per buffer per input
    __shared__ float4 sB[2][TILE_F4];   // total 36,864 B -> 4 blocks/CU

    const int tid  = threadIdx.x;
    const int lane = tid & 63;
    const int wid  = tid >> 6;
    const float4* a4 = reinterpret_cast<const float4*>(a);
    const float4* b4 = reinterpret_cast<const float4*>(b);
    const long long tile0 = (long long)blockIdx.x * TILES_PER_BLK;

    // 18 wave-load instructions per tile (9 chunks x 2 inputs), round-robin by
    // wave: waves 0,1 issue 5 each; waves 2,3 issue 4 each. LDS dest is the
    // wave-uniform chunk base; HW scatters lane i to base + i*16 (m104/m108).
    auto stage = [&](int t, int bufsel) {
        const long long base = (tile0 + t) * TILE_F4;
        for (int i = wid; i < 18; i += 4) {
            const int c = i >> 1;
            if (i & 1) gload16_lds_nt(b4 + base + c * 64 + lane, &sB[bufsel][c * 64]);
            else       gload16_lds_nt(a4 + base + c * 64 + lane, &sA[bufsel][c * 64]);
        }
    };

    stage(0, 0);
    double acc = 0.0;

    for (int t = 0; t < TILES_PER_BLK; ++t) {
        const int cur = t & 1;
        if (t + 1 < TILES_PER_BLK) {
            stage(t + 1, cur ^ 1);             // next tile stays in flight over compute
            // wait ONLY for tile t's loads (leave tile t+1's outstanding)
            if (wid < 2) asm volatile("s_waitcnt vmcnt(5)" ::: "memory");
            else         asm volatile("s_waitcnt vmcnt(4)" ::: "memory");
        } else {
            asm volatile("s_waitcnt vmcnt(0)" ::: "memory");
        }
        __builtin_amdgcn_s_barrier();           // raw barrier: no implicit vmcnt(0)
        __builtin_amdgcn_sched_barrier(0);      // keep ds_reads below the barrier

        // one sample per thread; float stride 9 is odd -> worst 2-way aliasing (free)
        const float* pa = reinterpret_cast<const float*>(&sA[cur][0]) + 9 * tid;
        const float* pb = reinterpret_cast<const float*>(&sB[cur][0]) + 9 * tid;
        float dot = 0.0f;
        #pragma unroll
        for (int j = 0; j < 9; ++j) dot = fmaf(pa[j], pb[j], dot);

        const long long s = (tile0 + t) * SAMP_PER_TILE + tid;
        if (s < nsamp) {
            float c = (dot - 1.0f) * 0.5f;
            c = fminf(fmaxf(c, -1.0f + EPSF), 1.0f - EPSF);
            acc += (double)acosf(c);
        }

        __builtin_amdgcn_sched_barrier(0);      // keep compute above barrier2
        __builtin_amdgcn_s_barrier();           // all waves done reading buf[cur]
                                                // before next iter re-stages into it
    }

    const double r = block_reduce(acc);
    if (threadIdx.x == 0) partial[blockIdx.x] = r;
}

__global__ __launch_bounds__(TPB) void geo_final(
    const double* __restrict__ partial, float* __restrict__ out,
    int n, double inv_n)
{
    double acc = 0.0;
    for (int i = threadIdx.x; i < n; i += TPB) acc += partial[i];
    const double r = block_reduce(acc);
    if (threadIdx.x == 0) out[0] = (float)(r * inv_n);
}

extern "C" void kernel_launch(void* const* d_in, const int* in_sizes, int n_in,
                              void* d_out, int out_size, void* d_ws, size_t ws_size,
                              hipStream_t stream) {
    const float* a = (const float*)d_in[0];   // ypred [B,3,3] f32
    const float* b = (const float*)d_in[1];   // ytrue [B,3,3] f32
    float* out = (float*)d_out;               // scalar f32
    const long long nsamp = in_sizes[0] / 9;

    double* partial = (double*)d_ws;          // NBLK doubles; all written every launch

    geo_partial<<<NBLK, TPB, 0, stream>>>(a, b, partial, nsamp);
    geo_final<<<1, TPB, 0, stream>>>(partial, out, NBLK, 1.0 / (double)nsamp);
}